// Round 3
// baseline (305.066 us; speedup 1.0000x reference)
//
#include <hip/hip_runtime.h>

// GlobalMaxAvgPool: segment max + segment mean, N=2e6, C=128, B=32, ids sorted.
// Memory-bound: 1.025 GB read -> floor ~164 us @ 6.3 TB/s.
// R2: wave-contiguous streams (each wave walks a contiguous row range, no
// inter-wave interleave), manual 8-deep float4 unroll (8 loads in flight),
// nontemporal loads (pure streaming, no reuse).

using f32x4 = __attribute__((ext_vector_type(4))) float;

#define INFF __builtin_huge_valf()

__device__ __forceinline__ unsigned enc_f32(float f) {
    unsigned u = __float_as_uint(f);
    return (u & 0x80000000u) ? ~u : (u | 0x80000000u);
}
__device__ __forceinline__ float dec_f32(unsigned e) {
    unsigned u = (e & 0x80000000u) ? (e & 0x7FFFFFFFu) : ~e;
    return __uint_as_float(u);
}

__device__ __forceinline__ int lower_bound_i(const int* __restrict__ a, int n, int v) {
    int lo = 0, hi = n;
    while (lo < hi) {
        int mid = (lo + hi) >> 1;
        if (a[mid] < v) lo = mid + 1; else hi = mid;
    }
    return lo;
}

// Kernel 0: re-init out accumulators (harness doesn't re-poison between replays)
// + segment start offsets seg_starts[0..B] into workspace.
__global__ void gp_prep(unsigned* out_u, float* out_f, int out_total, int C,
                        const int* __restrict__ ids, int N, int B,
                        int* __restrict__ seg_starts) {
    int i = blockIdx.x * blockDim.x + threadIdx.x;
    if (i < out_total) {
        int c = i % (2 * C);
        if (c < C) out_u[i] = 0x007FFFFFu;   // enc(-inf)
        else       out_f[i] = 0.0f;
    }
    if (i <= B) seg_starts[i] = lower_bound_i(ids, N, i);  // seg_starts[B]==N
}

__device__ __forceinline__ void gp_acc(f32x4& vmax, f32x4& vsum, f32x4 f) {
    vmax[0] = fmaxf(vmax[0], f[0]);
    vmax[1] = fmaxf(vmax[1], f[1]);
    vmax[2] = fmaxf(vmax[2], f[2]);
    vmax[3] = fmaxf(vmax[3], f[3]);
    vsum += f;
}

__device__ __forceinline__ void gp_flush(unsigned* __restrict__ omax,
                                         float* __restrict__ osum,
                                         int seg, int c0,
                                         const f32x4& vmax, const f32x4& vsum) {
    int base = seg * 256 + c0;   // out layout [B][2C], C==128
    atomicMax(&omax[base + 0], enc_f32(vmax[0]));
    atomicMax(&omax[base + 1], enc_f32(vmax[1]));
    atomicMax(&omax[base + 2], enc_f32(vmax[2]));
    atomicMax(&omax[base + 3], enc_f32(vmax[3]));
    atomicAdd(&osum[base + 128 + 0], vsum[0]);
    atomicAdd(&osum[base + 128 + 1], vsum[1]);
    atomicAdd(&osum[base + 128 + 2], vsum[2]);
    atomicAdd(&osum[base + 128 + 3], vsum[3]);
}

// C==128: 32 lanes x float4 = one row; each wave = 2 rows/step, contiguous walk.
__global__ __launch_bounds__(256, 8)
void gp_main(const float* __restrict__ feat,
             const int* __restrict__ seg_starts,
             unsigned* __restrict__ omax, float* __restrict__ osum,
             int N, int waveChunk, int B) {
    const int t     = threadIdx.x;
    const int wave  = t >> 6;          // 0..3
    const int slot2 = (t >> 5) & 1;    // row parity within wave
    const int lane5 = t & 31;
    const int c0    = lane5 * 4;

    __shared__ int sb[40];             // seg_starts[0..B]
    if (t <= B) sb[t] = seg_starts[t];
    __syncthreads();

    // this wave's contiguous row range
    int ws = (blockIdx.x * 4 + wave) * waveChunk;
    int we = ws + waveChunk;
    if (we > N) we = N;
    if (ws >= we) return;

    // segment containing ws (uniform per wave)
    int seg = 0;
    #pragma unroll
    for (int s = 1; s <= 32; ++s)
        if (s <= B && sb[s] <= ws) seg = s;

    const f32x4* __restrict__ frow = reinterpret_cast<const f32x4*>(feat);

    int rs = ws;
    while (rs < we) {
        int re = sb[seg + 1];
        if (re > we) re = we;
        if (rs + slot2 < re) {
            f32x4 vmax = {-INFF, -INFF, -INFF, -INFF};
            f32x4 vsum = {0.f, 0.f, 0.f, 0.f};
            int r = rs + slot2;
            // 8-deep: rows r..r+14 (wave covers rs..rs+15 = 8KB contiguous)
            for (; r + 14 < re; r += 16) {
                size_t b0 = (size_t)r * 32 + lane5;
                f32x4 f0 = __builtin_nontemporal_load(&frow[b0 +   0]);
                f32x4 f1 = __builtin_nontemporal_load(&frow[b0 +  64]);
                f32x4 f2 = __builtin_nontemporal_load(&frow[b0 + 128]);
                f32x4 f3 = __builtin_nontemporal_load(&frow[b0 + 192]);
                f32x4 f4 = __builtin_nontemporal_load(&frow[b0 + 256]);
                f32x4 f5 = __builtin_nontemporal_load(&frow[b0 + 320]);
                f32x4 f6 = __builtin_nontemporal_load(&frow[b0 + 384]);
                f32x4 f7 = __builtin_nontemporal_load(&frow[b0 + 448]);
                gp_acc(vmax, vsum, f0);
                gp_acc(vmax, vsum, f1);
                gp_acc(vmax, vsum, f2);
                gp_acc(vmax, vsum, f3);
                gp_acc(vmax, vsum, f4);
                gp_acc(vmax, vsum, f5);
                gp_acc(vmax, vsum, f6);
                gp_acc(vmax, vsum, f7);
            }
            for (; r < re; r += 2) {
                f32x4 f = __builtin_nontemporal_load(&frow[(size_t)r * 32 + lane5]);
                gp_acc(vmax, vsum, f);
            }
            gp_flush(omax, osum, seg, c0, vmax, vsum);
        }
        ++seg;
        rs = re;
    }
}

// One block per segment: decode max in place, divide sums by count.
__global__ void gp_final(float* out, const int* __restrict__ seg_starts, int C) {
    int b = blockIdx.x;
    int c = threadIdx.x;   // 0..C-1
    int cnt = seg_starts[b + 1] - seg_starts[b];
    unsigned* ou = reinterpret_cast<unsigned*>(out);
    int base = b * 2 * C;
    float mx = dec_f32(ou[base + c]);
    float s  = out[base + C + c];
    out[base + c]     = mx;
    out[base + C + c] = s / fmaxf((float)cnt, 1.0f);
}

extern "C" void kernel_launch(void* const* d_in, const int* in_sizes, int n_in,
                              void* d_out, int out_size, void* d_ws, size_t ws_size,
                              hipStream_t stream) {
    const float* feat = (const float*)d_in[0];
    const int*   ids  = (const int*)d_in[1];
    int N = in_sizes[1];
    int C = (N > 0) ? (in_sizes[0] / N) : 128;   // 128
    int B = out_size / (2 * C);                  // 32
    float*    out_f = (float*)d_out;
    unsigned* out_u = (unsigned*)d_out;
    int* seg_starts = (int*)d_ws;                // B+1 ints scratch

    int prep_threads = out_size > (B + 1) ? out_size : (B + 1);
    gp_prep<<<(prep_threads + 255) / 256, 256, 0, stream>>>(
        out_u, out_f, out_size, C, ids, N, B, seg_starts);

    const int blocks = 2048;                      // 8 blocks/CU, 32 waves/CU
    int wavesTotal = blocks * 4;
    int waveChunk = (N + wavesTotal - 1) / wavesTotal;
    waveChunk = (waveChunk + 1) & ~1;             // even -> 1KB-aligned wave streams
    gp_main<<<blocks, 256, 0, stream>>>(feat, seg_starts, out_u, out_f, N, waveChunk, B);

    gp_final<<<B, C, 0, stream>>>(out_f, seg_starts, C);
}

// Round 4
// 238.721 us; speedup vs baseline: 1.2779x; 1.2779x over previous
//
#include <hip/hip_runtime.h>

// GlobalMaxAvgPool: segment max + segment mean, N=2e6, C=128, B=32, ids sorted.
// Memory-bound: 1.025 GB read -> floor ~164 us @ 6.3 TB/s.
// R3: ZERO global atomics. gp_main writes per-(block,run) partials (128 max +
// 128 sum) to workspace via LDS block-reduce + plain stores; gp_reduce combines
// the contiguous slot range per segment deterministically. Theory: R0-R2 were
// all capped ~3.5 TB/s by the 4.2M-atomic burst onto 8K words, not by the
// read stream (pattern-insensitivity across R0/R1/R2 is the evidence).

using f32x4 = __attribute__((ext_vector_type(4))) float;
#define INFF __builtin_huge_valf()

#define BLOCKS 2048
#define MAXR   8          // max segment-runs per block (data: <=2)

// ws layout (bytes):
//   0      : int seg_starts[33]
//   256    : int hdr[BLOCKS*MAXR]
//   aligned: float part[BLOCKS*MAXR][256]   (128 max | 128 sum)
#define OFF_HDR   256
#define OFF_PART  (OFF_HDR + BLOCKS * MAXR * 4 + 256)

__device__ __forceinline__ int lower_bound_i(const int* __restrict__ a, int n, int v) {
    int lo = 0, hi = n;
    while (lo < hi) {
        int mid = (lo + hi) >> 1;
        if (a[mid] < v) lo = mid + 1; else hi = mid;
    }
    return lo;
}

// seg_starts[0..B] via binary search on sorted ids (33 threads, ~21 steps each)
__global__ void gp_prep(const int* __restrict__ ids, int N, int B,
                        int* __restrict__ seg_starts) {
    int i = threadIdx.x;
    if (i <= B) seg_starts[i] = lower_bound_i(ids, N, i);   // seg_starts[B]==N
}

// C==128: 32 lanes x float4 = one row; 8 row-slots x 8-row interleave per block.
// All run boundaries are block-uniform -> safe __syncthreads inside run loop.
__global__ __launch_bounds__(256, 8)
void gp_main(const float* __restrict__ feat,
             const int* __restrict__ seg_starts,
             int* __restrict__ hdr, float* __restrict__ part,
             int N, int chunk, int B) {
    const int t     = threadIdx.x;
    const int slot  = t >> 5;        // 0..7
    const int lane5 = t & 31;
    const int c0    = lane5 * 4;

    __shared__ int   sb[33];
    __shared__ float lmax[8][132];   // +4 pad
    __shared__ float lsum[8][132];

    if (t < 33) sb[t] = seg_starts[t];
    __syncthreads();

    int start = blockIdx.x * chunk;
    int end   = start + chunk;
    if (end > N) end = N;

    // segment containing start (uniform scan over 32 boundaries)
    int seg = 0;
    #pragma unroll
    for (int s = 1; s < 33; ++s)
        if (sb[s] <= start) seg = s;

    const f32x4* __restrict__ frow = reinterpret_cast<const f32x4*>(feat);

    int run = 0;
    int rs  = start;
    while (rs < end) {               // uniform loop
        int re = sb[seg + 1];
        if (re > end) re = end;

        f32x4 vmax = {-INFF, -INFF, -INFF, -INFF};
        f32x4 vsum = {0.f, 0.f, 0.f, 0.f};
        #pragma unroll 4
        for (int r = rs + slot; r < re; r += 8) {
            f32x4 f = frow[(size_t)r * 32 + lane5];   // 16B/lane coalesced
            vmax[0] = fmaxf(vmax[0], f[0]);
            vmax[1] = fmaxf(vmax[1], f[1]);
            vmax[2] = fmaxf(vmax[2], f[2]);
            vmax[3] = fmaxf(vmax[3], f[3]);
            vsum += f;
        }

        // block-level LDS reduce: 8 contributors per channel
        lmax[slot][c0 + 0] = vmax[0]; lmax[slot][c0 + 1] = vmax[1];
        lmax[slot][c0 + 2] = vmax[2]; lmax[slot][c0 + 3] = vmax[3];
        lsum[slot][c0 + 0] = vsum[0]; lsum[slot][c0 + 1] = vsum[1];
        lsum[slot][c0 + 2] = vsum[2]; lsum[slot][c0 + 3] = vsum[3];
        __syncthreads();

        if (run < MAXR) {
            if (t < 128) {
                float m  = lmax[0][t];
                float su = lsum[0][t];
                #pragma unroll
                for (int s = 1; s < 8; ++s) {
                    m   = fmaxf(m, lmax[s][t]);
                    su += lsum[s][t];
                }
                size_t base = (size_t)(blockIdx.x * MAXR + run) * 256;
                part[base + t]       = m;
                part[base + 128 + t] = su;
            }
            if (t == 0) hdr[blockIdx.x * MAXR + run] = seg;
        }
        __syncthreads();
        ++run; ++seg; rs = re;
    }
    // mark unused slots (deterministic every call; ws is not re-poisoned)
    if (t == 0)
        for (int r = run; r < MAXR; ++r) hdr[blockIdx.x * MAXR + r] = -1;
}

// One block per segment: slots for segment b live in blocks [s0/chunk, (s1-1)/chunk].
// Fixed accumulation order -> deterministic. Writes ALL of d_out (no init needed).
__global__ void gp_reduce(const int* __restrict__ seg_starts,
                          const int* __restrict__ hdr,
                          const float* __restrict__ part,
                          float* __restrict__ out, int chunk) {
    int b = blockIdx.x;     // segment
    int t = threadIdx.x;    // 0..255 ; t<128: max channel t ; t>=128: sum channel t-128
    int s0 = seg_starts[b], s1 = seg_starts[b + 1];
    int cnt = s1 - s0;
    float m  = -INFF;
    float su = 0.f;
    if (cnt > 0) {
        int kb0 = s0 / chunk;
        int kb1 = (s1 - 1) / chunk;
        for (int kb = kb0; kb <= kb1; ++kb) {
            #pragma unroll
            for (int r = 0; r < MAXR; ++r) {
                if (hdr[kb * MAXR + r] == b) {
                    float v = part[(size_t)(kb * MAXR + r) * 256 + t];
                    m   = fmaxf(m, v);   // valid when t<128
                    su += v;             // valid when t>=128
                }
            }
        }
    }
    out[b * 256 + t] = (t < 128) ? m : su / fmaxf((float)cnt, 1.0f);
}

extern "C" void kernel_launch(void* const* d_in, const int* in_sizes, int n_in,
                              void* d_out, int out_size, void* d_ws, size_t ws_size,
                              hipStream_t stream) {
    const float* feat = (const float*)d_in[0];
    const int*   ids  = (const int*)d_in[1];
    int N = in_sizes[1];
    int C = (N > 0) ? (in_sizes[0] / N) : 128;   // 128
    int B = out_size / (2 * C);                  // 32
    float* out_f = (float*)d_out;

    char* ws = (char*)d_ws;
    int*   seg_starts = (int*)ws;
    int*   hdr        = (int*)(ws + OFF_HDR);
    float* part       = (float*)(ws + OFF_PART);

    gp_prep<<<1, 64, 0, stream>>>(ids, N, B, seg_starts);

    int chunk = (N + BLOCKS - 1) / BLOCKS;       // 977
    gp_main<<<BLOCKS, 256, 0, stream>>>(feat, seg_starts, hdr, part, N, chunk, B);

    gp_reduce<<<B, 256, 0, stream>>>(seg_starts, hdr, part, out_f, chunk);
}